// Round 4
// baseline (300.877 us; speedup 1.0000x reference)
//
#include <hip/hip_runtime.h>
#include <math.h>

typedef unsigned short ushort_t;
typedef __attribute__((ext_vector_type(8))) __bf16 bf16x8;
typedef __attribute__((ext_vector_type(4))) float floatx4;

#define B_    256
#define I_    1152
#define J_    10
#define DIN_  8
#define DOUT_ 16
#define K_    (I_*DIN_)     // 9216
#define N_    (J_*DOUT_)    // 160
#define KSPLIT 16           // total split-K per output tile
#define KCHUNK (K_/KSPLIT)  // 576 (72 i's per wave)
#define KSTEPS (KCHUNK/32)  // 18

static __device__ __forceinline__ ushort_t f2bf(float f) {
    unsigned int u = __float_as_uint(f);
    u += 0x7fffu + ((u >> 16) & 1u);     // RNE
    return (ushort_t)(u >> 16);
}
static __device__ __forceinline__ float bf2f(ushort_t h) {
    return __uint_as_float(((unsigned int)h) << 16);
}

// ---------------------------------------------------------------------------
// Round-19 s-GEMM: r2's L2-resident geometry, atomic-free reduction.
//   grid 1280 x 128 thr (2 waves). kb = blk&7 = K-slice of 1152 rows AND the
//   XCD (heuristic): per-XCD working set = x[:,kb] 1.18MB + W[kb,:] 0.74MB =
//   1.9MB < 4MB L2 -> the 10x/16x cross-block re-reads are L2 hits, not LLC
//   traffic (r0's 5.3MB rectangle thrashed -> ~189MB from LLC ~ 30+us).
//   Reduction (fixes r2's 70-90us tail of 327k element-atomics): each block
//   stores its 16x16 fp32 partial to pbuf (agent-scope, per-iter-disjoint
//   buffer -> no stale-L2 hazard) + ONE ticket atomic per block (160/tile-
//   generation total). 8th arrival re-reads 8x256 partials, squashes, emits.
//   In-loop Dekker hi/lo 3-MFMA fp32-equivalent math (r3 proved VALU is free).
// ---------------------------------------------------------------------------
__global__ __launch_bounds__(128)
void gemm_s_part_kernel(const float* __restrict__ x, const float* __restrict__ W,
                        const float* __restrict__ blog, float* __restrict__ s_out,
                        ushort_t* __restrict__ Sbt_hi, ushort_t* __restrict__ Sbt_lo,
                        float* __restrict__ pbuf, unsigned int* __restrict__ cnt,
                        const int iter)
{
    const int tid  = threadIdx.x;          // 0..127
    const int blk  = blockIdx.x;           // 0..1279
    const int kb   = blk & 7;              // K-slice / XCD (perf-only heuristic)
    const int tile = blk >> 3;             // 0..159
    const int mb   = tile & 15;            // 0..15
    const int nt   = tile >> 4;            // 0..9
    const int lane = tid & 63;
    const int w    = tid >> 6;             // 0..1
    const int kc   = kb * 2 + w;           // 0..15: wave's k-chunk index

    __shared__ float   c_lds[144];         // c[i][nt] for this block's 144 i's
    __shared__ floatx4 part[2 * 64];
    __shared__ int     last_s;

    if (iter > 0) {
        for (int r2 = tid; r2 < 144; r2 += 128) {
            const float* br = blog + (size_t)(kb * 144 + r2) * J_;
            float bv[J_];
            float mx = -1e30f;
            #pragma unroll
            for (int j = 0; j < J_; ++j) { bv[j] = br[j]; mx = fmaxf(mx, bv[j]); }
            float sum = 0.f;
            #pragma unroll
            for (int j = 0; j < J_; ++j) { bv[j] = __expf(bv[j] - mx); sum += bv[j]; }
            c_lds[r2] = bv[nt] / sum;
        }
        __syncthreads();
    }

    {
        const int r = lane & 15, q = lane >> 4;
        const float* ap = x + (size_t)(mb * 16 + r) * K_ + kc * KCHUNK + 8 * q;
        // B row (j=nt, o=r); k-frag covers i = kc*72 + 4s + q, d=0..7
        const float* wp = W + (((size_t)(kc * 72 + q) * J_ + nt) * DOUT_ + r) * DIN_;
        const size_t wstep = (size_t)4 * J_ * DOUT_ * DIN_;
        floatx4 acc = {0.f, 0.f, 0.f, 0.f};

        // 2-deep prefetch ring (fully unrolled loop -> static indices)
        float4 bxa0[2], bxa1[2], bw0[2], bw1[2];
        #pragma unroll
        for (int s = 0; s < 2; ++s) {
            bxa0[s] = *(const float4*)(ap + s * 32);
            bxa1[s] = *(const float4*)(ap + s * 32 + 4);
            bw0[s]  = *(const float4*)(wp + s * wstep);
            bw1[s]  = *(const float4*)(wp + s * wstep + 4);
        }
        #pragma unroll
        for (int s = 0; s < KSTEPS; ++s) {
            float4 xa0 = bxa0[s & 1], xa1 = bxa1[s & 1];
            float4 w0  = bw0[s & 1],  w1  = bw1[s & 1];
            if (s + 2 < KSTEPS) {
                bxa0[s & 1] = *(const float4*)(ap + (s + 2) * 32);
                bxa1[s & 1] = *(const float4*)(ap + (s + 2) * 32 + 4);
                bw0[s & 1]  = *(const float4*)(wp + (s + 2) * wstep);
                bw1[s & 1]  = *(const float4*)(wp + (s + 2) * wstep + 4);
            }
            float cs = (iter == 0) ? 0.1f : c_lds[w * 72 + 4 * s + q];
            float xv[8]  = {xa0.x, xa0.y, xa0.z, xa0.w, xa1.x, xa1.y, xa1.z, xa1.w};
            float wvv[8] = {w0.x, w0.y, w0.z, w0.w, w1.x, w1.y, w1.z, w1.w};
            bf16x8 ah, al, bh, bl;
            #pragma unroll
            for (int e = 0; e < 8; ++e) {
                float xe = xv[e];
                __bf16 h = (__bf16)xe;
                ah[e] = h;
                al[e] = (__bf16)(xe - (float)h);
                float pe = wvv[e] * cs;
                __bf16 g = (__bf16)pe;
                bh[e] = g;
                bl[e] = (__bf16)(pe - (float)g);
            }
            acc = __builtin_amdgcn_mfma_f32_16x16x32_bf16(ah, bh, acc, 0, 0, 0);
            acc = __builtin_amdgcn_mfma_f32_16x16x32_bf16(al, bh, acc, 0, 0, 0);
            acc = __builtin_amdgcn_mfma_f32_16x16x32_bf16(ah, bl, acc, 0, 0, 0);
        }
        part[w * 64 + lane] = acc;
    }
    __syncthreads();

    // ---- in-block pair-reduce -> store 16x16 partial (agent scope) ----
    const int row  = tid >> 3;             // 0..15 (b_local)
    const int col2 = (tid & 7) * 2;        // o pair base
    {
        const size_t pb = (size_t)(tile * 8 + kb) * 256 + row * 16 + col2;
        #pragma unroll
        for (int h = 0; h < 2; ++h) {
            const int o      = col2 + h;
            const int lane_c = ((row >> 2) << 4) | o;   // C/D: col=lane&15, row=quad*4+reg
            const int reg    = row & 3;
            float v = part[lane_c][reg] + part[64 + lane_c][reg];
            __hip_atomic_store(&pbuf[pb + h], v, __ATOMIC_RELAXED,
                               __HIP_MEMORY_SCOPE_AGENT);
        }
    }
    __syncthreads();                       // all 128 threads' stores issued+drained
    if (tid == 0) {
        __threadfence();                   // release: partials visible device-wide
        unsigned int old = atomicAdd(&cnt[tile], 1u);   // monotone across iters
        last_s = (old == (unsigned int)(iter * 8 + 7));
    }
    __syncthreads();
    if (!last_s) return;

    // ---- last arrival: sum 8 partials, squash, emit ----
    __threadfence();                       // acquire: see siblings' partials
    float v[2] = {0.f, 0.f};
    #pragma unroll
    for (int u = 0; u < 8; ++u) {
        const size_t pb = (size_t)(tile * 8 + u) * 256 + row * 16 + col2;
        v[0] += __hip_atomic_load(&pbuf[pb],     __ATOMIC_RELAXED, __HIP_MEMORY_SCOPE_AGENT);
        v[1] += __hip_atomic_load(&pbuf[pb + 1], __ATOMIC_RELAXED, __HIP_MEMORY_SCOPE_AGENT);
    }
    float sq = v[0] * v[0] + v[1] * v[1];
    #pragma unroll
    for (int off = 1; off < 8; off <<= 1)   // 8-thread group = one b row (16 o's)
        sq += __shfl_xor(sq, off, 8);
    float l2 = sqrtf(sq);
    float scale = l2 / (1.f + sq);
    const int b = mb * 16 + row;
    #pragma unroll
    for (int h = 0; h < 2; ++h) {
        float val = v[h] * scale;
        const int jo = nt * 16 + col2 + h;
        if (iter == 2) {
            s_out[(size_t)b * N_ + jo] = val;
        } else {
            ushort_t hi = f2bf(val);
            Sbt_hi[(size_t)jo * B_ + b] = hi;
            Sbt_lo[(size_t)jo * B_ + b] = f2bf(val - bf2f(hi));
        }
    }
}

// ---------------------------------------------------------------------------
// b-update GEMM: T2 = X^T @ S' (M=9216 N=160 K=256). Each wave: one mt and
// TWO j's (A-side x loads + Dekker split shared). A read directly from fp32 x
// (quarter-wave-coalesced 64B lines) with 1-step prefetch; B from Sbt hi/lo.
// XCD-contiguous wv remap (validated in round 2): blk&7 owns a contiguous
// 72-mt range -> per-XCD x^T slice 1.18MB + Sbt 160KB stays L2-resident.
// 3 MFMAs per j per step => fp32-equivalent. Epilogue contracts with fp32 W;
// unique (i,j) writer per half-wave. first!=0: blog = val.
// ---------------------------------------------------------------------------
__global__ __launch_bounds__(256)
void gemm_bupd_kernel(const float* __restrict__ x,
                      const ushort_t* __restrict__ Sbt_hi, const ushort_t* __restrict__ Sbt_lo,
                      const float* __restrict__ W, float* __restrict__ blog,
                      const int first)
{
    // bijective remap: XCD (blk&7) gets wv in [xcd*360, xcd*360+360) -> mt
    // in [xcd*72, xcd*72+72) contiguous (720 blocks, 720%8==0).
    int wv   = (blockIdx.x & 7) * 360 + (blockIdx.x >> 3) * 4 + (threadIdx.x >> 6);
    int lane = threadIdx.x & 63;
    int mt = wv / 5;                                  // 0..575
    int jp = wv - mt * 5;                             // j-pair: j0=2jp, j1=2jp+1
    int j0 = jp * 2, j1 = jp * 2 + 1;
    int r = lane & 15, q = lane >> 4;
    const float* xp = x + (size_t)(8 * q) * K_ + (mt * 16 + r);   // + (s*32+e)*K_
    size_t b0off = (size_t)(j0 * 16 + r) * B_ + 8 * q;
    size_t b1off = (size_t)(j1 * 16 + r) * B_ + 8 * q;
    floatx4 acc0 = {0.f, 0.f, 0.f, 0.f};
    floatx4 acc1 = {0.f, 0.f, 0.f, 0.f};

    float xcur[8], xnxt[8];
    #pragma unroll
    for (int e = 0; e < 8; ++e) xcur[e] = xp[(size_t)e * K_];
    #pragma unroll
    for (int s = 0; s < B_ / 32; ++s) {
        if (s + 1 < B_ / 32) {               // prefetch next step's x column slice
            #pragma unroll
            for (int e = 0; e < 8; ++e)
                xnxt[e] = xp[(size_t)((s + 1) * 32 + e) * K_];
        }
        bf16x8 ah, al;
        #pragma unroll
        for (int e = 0; e < 8; ++e) {
            float v = xcur[e];
            __bf16 h = (__bf16)v;
            ah[e] = h;
            al[e] = (__bf16)(v - (float)h);
        }
        bf16x8 bh0 = *(const bf16x8*)(Sbt_hi + b0off + s * 32);
        bf16x8 bl0 = *(const bf16x8*)(Sbt_lo + b0off + s * 32);
        bf16x8 bh1 = *(const bf16x8*)(Sbt_hi + b1off + s * 32);
        bf16x8 bl1 = *(const bf16x8*)(Sbt_lo + b1off + s * 32);
        acc0 = __builtin_amdgcn_mfma_f32_16x16x32_bf16(ah, bh0, acc0, 0, 0, 0);
        acc0 = __builtin_amdgcn_mfma_f32_16x16x32_bf16(al, bh0, acc0, 0, 0, 0);
        acc0 = __builtin_amdgcn_mfma_f32_16x16x32_bf16(ah, bl0, acc0, 0, 0, 0);
        acc1 = __builtin_amdgcn_mfma_f32_16x16x32_bf16(ah, bh1, acc1, 0, 0, 0);
        acc1 = __builtin_amdgcn_mfma_f32_16x16x32_bf16(al, bh1, acc1, 0, 0, 0);
        acc1 = __builtin_amdgcn_mfma_f32_16x16x32_bf16(ah, bl1, acc1, 0, 0, 0);
        #pragma unroll
        for (int e = 0; e < 8; ++e) xcur[e] = xnxt[e];
    }
    // rows q*4+reg -> i = mt*2 + (q>>1), d = (q&1)*4 + reg; col -> o = lane&15
    int i  = mt * 2 + (q >> 1);
    int d0 = (q & 1) * 4;
    int o  = lane & 15;
    int iw = mt * 2 + (lane >> 5);
    {
        const float4 w4 = *(const float4*)(W + ((((size_t)i * J_ + j0) * DOUT_ + o) * DIN_ + d0));
        float val = acc0[0] * w4.x + acc0[1] * w4.y + acc0[2] * w4.z + acc0[3] * w4.w;
        #pragma unroll
        for (int off = 1; off < 32; off <<= 1)
            val += __shfl_xor(val, off, 32);
        if ((lane & 31) == 0) {
            float* dst = blog + (size_t)iw * J_ + j0;
            if (first) *dst = val; else *dst += val;
        }
    }
    {
        const float4 w4 = *(const float4*)(W + ((((size_t)i * J_ + j1) * DOUT_ + o) * DIN_ + d0));
        float val = acc1[0] * w4.x + acc1[1] * w4.y + acc1[2] * w4.z + acc1[3] * w4.w;
        #pragma unroll
        for (int off = 1; off < 32; off <<= 1)
            val += __shfl_xor(val, off, 32);
        if ((lane & 31) == 0) {
            float* dst = blog + (size_t)iw * J_ + j1;
            if (first) *dst = val; else *dst += val;
        }
    }
}

// ---------------------------------------------------------------------------
extern "C" void kernel_launch(void* const* d_in, const int* in_sizes, int n_in,
                              void* d_out, int out_size, void* d_ws, size_t ws_size,
                              hipStream_t stream)
{
    const float* x = (const float*)d_in[0];   // [B, I, DIN]
    const float* W = (const float*)d_in[1];   // [I, J, DOUT, DIN]
    float* s_out = (float*)d_out;             // [B, J, DOUT]

    char* ws = (char*)d_ws;
    ushort_t*     Sbt_hi = (ushort_t*)(ws);                 //    81,920 B
    ushort_t*     Sbt_lo = (ushort_t*)(ws + 81920);         //    81,920 B
    float*        blog   = (float*)   (ws + 163840);        //    46,080 B
    float*        pbuf0  = (float*)   (ws + 262144);        // 1,310,720 B
    float*        pbuf1  = (float*)   (ws + 1572864);       // 1,310,720 B
    float*        pbuf2  = (float*)   (ws + 2883584);       // 1,310,720 B
    unsigned int* cnt    = (unsigned int*)(ws + 4194304);   //       640 B (~4.2 MB)
    float* pbufs[3] = {pbuf0, pbuf1, pbuf2};

    // zero tickets once per call (640 B, graph-capturable)
    (void)hipMemsetAsync(ws + 4194304, 0, 640, stream);

    for (int it = 0; it < 3; ++it) {
        gemm_s_part_kernel<<<1280, 128, 0, stream>>>(x, W, blog, s_out,
                                                     Sbt_hi, Sbt_lo,
                                                     pbufs[it], cnt, it);
        if (it < 2)
            gemm_bupd_kernel<<<720, 256, 0, stream>>>(x, Sbt_hi, Sbt_lo,
                                                      W, blog, it == 0 ? 1 : 0);
    }
}

// Round 5
// 141.658 us; speedup vs baseline: 2.1240x; 2.1240x over previous
//
#include <hip/hip_runtime.h>
#include <math.h>

typedef unsigned short ushort_t;
typedef __attribute__((ext_vector_type(8))) __bf16 bf16x8;
typedef __attribute__((ext_vector_type(4))) float floatx4;

#define B_    256
#define I_    1152
#define J_    10
#define DIN_  8
#define DOUT_ 16
#define K_    (I_*DIN_)     // 9216
#define N_    (J_*DOUT_)    // 160
#define KSPLIT 16           // total split-K per output tile
#define KCHUNK (K_/KSPLIT)  // 576 (72 i's per wave)
#define KSTEPS (KCHUNK/32)  // 18

static __device__ __forceinline__ ushort_t f2bf(float f) {
    unsigned int u = __float_as_uint(f);
    u += 0x7fffu + ((u >> 16) & 1u);     // RNE
    return (ushort_t)(u >> 16);
}
static __device__ __forceinline__ float bf2f(ushort_t h) {
    return __uint_as_float(((unsigned int)h) << 16);
}

// ---------------------------------------------------------------------------
// Round-20 s-GEMM, stage 1: SYNC-FREE partials (A/B test vs r4's fenced
// version — identical geometry & loads, all cross-block sync deleted).
//   grid 1280 x 128 thr (2 waves). kb = blk&7 = K-slice AND XCD (heuristic):
//   per-XCD working set = x[:,kb] 1.18MB + W[kb,:] 0.74MB = 1.9MB < 4MB L2.
//   Each block plain-stores its 16x16 fp32 partial to pbuf[blk] and exits.
//   No fences, no tickets, no atomics — the r2/r4 ~95us pathology was
//   (theory) 1440 per-block threadfences issuing L2 writeback/invalidate,
//   destroying the L2 working set. Kernel-boundary coherence replaces them.
//   In-loop Dekker hi/lo 3-MFMA fp32-equivalent math; 2-deep prefetch ring.
// ---------------------------------------------------------------------------
__global__ __launch_bounds__(128)
void gemm_s_part_kernel(const float* __restrict__ x, const float* __restrict__ W,
                        const float* __restrict__ blog,
                        float* __restrict__ pbuf, const int iter)
{
    const int tid  = threadIdx.x;          // 0..127
    const int blk  = blockIdx.x;           // 0..1279
    const int kb   = blk & 7;              // K-slice / XCD (perf-only heuristic)
    const int tile = blk >> 3;             // 0..159
    const int mb   = tile & 15;            // 0..15
    const int nt   = tile >> 4;            // 0..9
    const int lane = tid & 63;
    const int w    = tid >> 6;             // 0..1
    const int kc   = kb * 2 + w;           // 0..15: wave's k-chunk index

    __shared__ float   c_lds[144];         // c[i][nt] for this block's 144 i's
    __shared__ floatx4 part[2 * 64];

    if (iter > 0) {
        for (int r2 = tid; r2 < 144; r2 += 128) {
            const float* br = blog + (size_t)(kb * 144 + r2) * J_;
            float bv[J_];
            float mx = -1e30f;
            #pragma unroll
            for (int j = 0; j < J_; ++j) { bv[j] = br[j]; mx = fmaxf(mx, bv[j]); }
            float sum = 0.f;
            #pragma unroll
            for (int j = 0; j < J_; ++j) { bv[j] = __expf(bv[j] - mx); sum += bv[j]; }
            c_lds[r2] = bv[nt] / sum;
        }
        __syncthreads();
    }

    {
        const int r = lane & 15, q = lane >> 4;
        const float* ap = x + (size_t)(mb * 16 + r) * K_ + kc * KCHUNK + 8 * q;
        // B row (j=nt, o=r); k-frag covers i = kc*72 + 4s + q, d=0..7
        const float* wp = W + (((size_t)(kc * 72 + q) * J_ + nt) * DOUT_ + r) * DIN_;
        const size_t wstep = (size_t)4 * J_ * DOUT_ * DIN_;
        floatx4 acc = {0.f, 0.f, 0.f, 0.f};

        // 2-deep prefetch ring (fully unrolled loop -> static indices)
        float4 bxa0[2], bxa1[2], bw0[2], bw1[2];
        #pragma unroll
        for (int s = 0; s < 2; ++s) {
            bxa0[s] = *(const float4*)(ap + s * 32);
            bxa1[s] = *(const float4*)(ap + s * 32 + 4);
            bw0[s]  = *(const float4*)(wp + s * wstep);
            bw1[s]  = *(const float4*)(wp + s * wstep + 4);
        }
        #pragma unroll
        for (int s = 0; s < KSTEPS; ++s) {
            float4 xa0 = bxa0[s & 1], xa1 = bxa1[s & 1];
            float4 w0  = bw0[s & 1],  w1  = bw1[s & 1];
            if (s + 2 < KSTEPS) {
                bxa0[s & 1] = *(const float4*)(ap + (s + 2) * 32);
                bxa1[s & 1] = *(const float4*)(ap + (s + 2) * 32 + 4);
                bw0[s & 1]  = *(const float4*)(wp + (s + 2) * wstep);
                bw1[s & 1]  = *(const float4*)(wp + (s + 2) * wstep + 4);
            }
            float cs = (iter == 0) ? 0.1f : c_lds[w * 72 + 4 * s + q];
            float xv[8]  = {xa0.x, xa0.y, xa0.z, xa0.w, xa1.x, xa1.y, xa1.z, xa1.w};
            float wvv[8] = {w0.x, w0.y, w0.z, w0.w, w1.x, w1.y, w1.z, w1.w};
            bf16x8 ah, al, bh, bl;
            #pragma unroll
            for (int e = 0; e < 8; ++e) {
                float xe = xv[e];
                __bf16 h = (__bf16)xe;
                ah[e] = h;
                al[e] = (__bf16)(xe - (float)h);
                float pe = wvv[e] * cs;
                __bf16 g = (__bf16)pe;
                bh[e] = g;
                bl[e] = (__bf16)(pe - (float)g);
            }
            acc = __builtin_amdgcn_mfma_f32_16x16x32_bf16(ah, bh, acc, 0, 0, 0);
            acc = __builtin_amdgcn_mfma_f32_16x16x32_bf16(al, bh, acc, 0, 0, 0);
            acc = __builtin_amdgcn_mfma_f32_16x16x32_bf16(ah, bl, acc, 0, 0, 0);
        }
        part[w * 64 + lane] = acc;
    }
    __syncthreads();

    // ---- in-block pair-reduce -> plain store of 16x16 partial, exit ----
    const int row  = tid >> 3;             // 0..15 (b_local)
    const int col2 = (tid & 7) * 2;        // o pair base
    float2 v2;
    #pragma unroll
    for (int h = 0; h < 2; ++h) {
        const int o      = col2 + h;
        const int lane_c = ((row >> 2) << 4) | o;   // C/D: col=lane&15, row=quad*4+reg
        const int reg    = row & 3;
        ((float*)&v2)[h] = part[lane_c][reg] + part[64 + lane_c][reg];
    }
    *(float2*)(pbuf + (size_t)blk * 256 + row * 16 + col2) = v2;
}

// ---------------------------------------------------------------------------
// Round-20 stage 2: reduce 8 k-slice partials per tile + squash + emit.
// 160 blocks x 256 thr; reads 1.3MB (fresh from stage 1, L2/LLC-hot).
// Kernel boundary provides the cross-XCD coherence stage 1 no longer pays for.
// ---------------------------------------------------------------------------
__global__ __launch_bounds__(256)
void reduce_squash_kernel(const float* __restrict__ pbuf, float* __restrict__ s_out,
                          ushort_t* __restrict__ Sbt_hi, ushort_t* __restrict__ Sbt_lo,
                          const int iter)
{
    const int tile = blockIdx.x;           // 0..159 (same mapping as stage 1)
    const int mb   = tile & 15;
    const int nt   = tile >> 4;
    const int t    = threadIdx.x;          // 0..255
    const int row  = t >> 4;               // 0..15 (b_local)
    const int o    = t & 15;               // 0..15

    const float* pb = pbuf + (size_t)tile * 8 * 256 + row * 16 + o;
    float v = 0.f;
    #pragma unroll
    for (int u = 0; u < 8; ++u)
        v += pb[u * 256];

    float sq = v * v;
    #pragma unroll
    for (int off = 1; off < 16; off <<= 1)  // 16 consecutive lanes = one b row
        sq += __shfl_xor(sq, off, 16);
    float l2 = sqrtf(sq);
    float val = v * (l2 / (1.f + sq));
    const int b  = mb * 16 + row;
    const int jo = nt * 16 + o;
    if (iter == 2) {
        s_out[(size_t)b * N_ + jo] = val;
    } else {
        ushort_t hi = f2bf(val);
        Sbt_hi[(size_t)jo * B_ + b] = hi;
        Sbt_lo[(size_t)jo * B_ + b] = f2bf(val - bf2f(hi));
    }
}

// ---------------------------------------------------------------------------
// b-update GEMM: T2 = X^T @ S' (M=9216 N=160 K=256). Each wave: one mt and
// TWO j's (A-side x loads + Dekker split shared). A read directly from fp32 x
// (quarter-wave-coalesced 64B lines) with 1-step prefetch; B from Sbt hi/lo.
// XCD-contiguous wv remap (validated r2/r4): blk&7 owns a contiguous 72-mt
// range -> per-XCD x^T slice 1.18MB + Sbt 160KB stays L2-resident.
// 3 MFMAs per j per step => fp32-equivalent. Epilogue contracts with fp32 W;
// unique (i,j) writer per half-wave. first!=0: blog = val.
// ---------------------------------------------------------------------------
__global__ __launch_bounds__(256)
void gemm_bupd_kernel(const float* __restrict__ x,
                      const ushort_t* __restrict__ Sbt_hi, const ushort_t* __restrict__ Sbt_lo,
                      const float* __restrict__ W, float* __restrict__ blog,
                      const int first)
{
    // bijective remap: XCD (blk&7) gets wv in [xcd*360, xcd*360+360) -> mt
    // in [xcd*72, xcd*72+72) contiguous (720 blocks, 720%8==0).
    int wv   = (blockIdx.x & 7) * 360 + (blockIdx.x >> 3) * 4 + (threadIdx.x >> 6);
    int lane = threadIdx.x & 63;
    int mt = wv / 5;                                  // 0..575
    int jp = wv - mt * 5;                             // j-pair: j0=2jp, j1=2jp+1
    int j0 = jp * 2, j1 = jp * 2 + 1;
    int r = lane & 15, q = lane >> 4;
    const float* xp = x + (size_t)(8 * q) * K_ + (mt * 16 + r);   // + (s*32+e)*K_
    size_t b0off = (size_t)(j0 * 16 + r) * B_ + 8 * q;
    size_t b1off = (size_t)(j1 * 16 + r) * B_ + 8 * q;
    floatx4 acc0 = {0.f, 0.f, 0.f, 0.f};
    floatx4 acc1 = {0.f, 0.f, 0.f, 0.f};

    float xcur[8], xnxt[8];
    #pragma unroll
    for (int e = 0; e < 8; ++e) xcur[e] = xp[(size_t)e * K_];
    #pragma unroll
    for (int s = 0; s < B_ / 32; ++s) {
        if (s + 1 < B_ / 32) {               // prefetch next step's x column slice
            #pragma unroll
            for (int e = 0; e < 8; ++e)
                xnxt[e] = xp[(size_t)((s + 1) * 32 + e) * K_];
        }
        bf16x8 ah, al;
        #pragma unroll
        for (int e = 0; e < 8; ++e) {
            float v = xcur[e];
            __bf16 h = (__bf16)v;
            ah[e] = h;
            al[e] = (__bf16)(v - (float)h);
        }
        bf16x8 bh0 = *(const bf16x8*)(Sbt_hi + b0off + s * 32);
        bf16x8 bl0 = *(const bf16x8*)(Sbt_lo + b0off + s * 32);
        bf16x8 bh1 = *(const bf16x8*)(Sbt_hi + b1off + s * 32);
        bf16x8 bl1 = *(const bf16x8*)(Sbt_lo + b1off + s * 32);
        acc0 = __builtin_amdgcn_mfma_f32_16x16x32_bf16(ah, bh0, acc0, 0, 0, 0);
        acc0 = __builtin_amdgcn_mfma_f32_16x16x32_bf16(al, bh0, acc0, 0, 0, 0);
        acc0 = __builtin_amdgcn_mfma_f32_16x16x32_bf16(ah, bl0, acc0, 0, 0, 0);
        acc1 = __builtin_amdgcn_mfma_f32_16x16x32_bf16(ah, bh1, acc1, 0, 0, 0);
        acc1 = __builtin_amdgcn_mfma_f32_16x16x32_bf16(al, bh1, acc1, 0, 0, 0);
        acc1 = __builtin_amdgcn_mfma_f32_16x16x32_bf16(ah, bl1, acc1, 0, 0, 0);
        #pragma unroll
        for (int e = 0; e < 8; ++e) xcur[e] = xnxt[e];
    }
    // rows q*4+reg -> i = mt*2 + (q>>1), d = (q&1)*4 + reg; col -> o = lane&15
    int i  = mt * 2 + (q >> 1);
    int d0 = (q & 1) * 4;
    int o  = lane & 15;
    int iw = mt * 2 + (lane >> 5);
    {
        const float4 w4 = *(const float4*)(W + ((((size_t)i * J_ + j0) * DOUT_ + o) * DIN_ + d0));
        float val = acc0[0] * w4.x + acc0[1] * w4.y + acc0[2] * w4.z + acc0[3] * w4.w;
        #pragma unroll
        for (int off = 1; off < 32; off <<= 1)
            val += __shfl_xor(val, off, 32);
        if ((lane & 31) == 0) {
            float* dst = blog + (size_t)iw * J_ + j0;
            if (first) *dst = val; else *dst += val;
        }
    }
    {
        const float4 w4 = *(const float4*)(W + ((((size_t)i * J_ + j1) * DOUT_ + o) * DIN_ + d0));
        float val = acc1[0] * w4.x + acc1[1] * w4.y + acc1[2] * w4.z + acc1[3] * w4.w;
        #pragma unroll
        for (int off = 1; off < 32; off <<= 1)
            val += __shfl_xor(val, off, 32);
        if ((lane & 31) == 0) {
            float* dst = blog + (size_t)iw * J_ + j1;
            if (first) *dst = val; else *dst += val;
        }
    }
}

// ---------------------------------------------------------------------------
extern "C" void kernel_launch(void* const* d_in, const int* in_sizes, int n_in,
                              void* d_out, int out_size, void* d_ws, size_t ws_size,
                              hipStream_t stream)
{
    const float* x = (const float*)d_in[0];   // [B, I, DIN]
    const float* W = (const float*)d_in[1];   // [I, J, DOUT, DIN]
    float* s_out = (float*)d_out;             // [B, J, DOUT]

    char* ws = (char*)d_ws;
    ushort_t* Sbt_hi = (ushort_t*)(ws);                 //    81,920 B
    ushort_t* Sbt_lo = (ushort_t*)(ws + 81920);         //    81,920 B
    float*    blog   = (float*)   (ws + 163840);        //    46,080 B
    float*    pbuf   = (float*)   (ws + 262144);        // 1,310,720 B (~1.6 MB)

    for (int it = 0; it < 3; ++it) {
        gemm_s_part_kernel<<<1280, 128, 0, stream>>>(x, W, blog, pbuf, it);
        reduce_squash_kernel<<<160, 256, 0, stream>>>(pbuf, s_out,
                                                      Sbt_hi, Sbt_lo, it);
        if (it < 2)
            gemm_bupd_kernel<<<720, 256, 0, stream>>>(x, Sbt_hi, Sbt_lo,
                                                      W, blog, it == 0 ? 1 : 0);
    }
}